// Round 4
// baseline (482.993 us; speedup 1.0000x reference)
//
#include <hip/hip_runtime.h>
#include <math.h>
#include <stdint.h>

// Problem shape (fixed by setup_inputs): P=512, R=256, S=256, K=3, threshold=0.
#define Pn 512
#define Rn 256
#define Sn 256

typedef unsigned long long u64;
typedef unsigned int u32;

// Monotonic float -> u32 map (order-preserving for all finite floats).
__device__ __forceinline__ u32 mono(float f) {
  u32 u = __float_as_uint(f);
  return (u & 0x80000000u) ? ~u : (u | 0x80000000u);
}
__device__ __forceinline__ float unmono(u32 m) {
  u32 bits = (m & 0x80000000u) ? (m & 0x7FFFFFFFu) : ~m;
  return __uint_as_float(bits);
}
// Packed sort key: value-monotonic bits high, ~index low.
// Larger key = larger value; equal value -> smaller index wins (lax.top_k).
__device__ __forceinline__ u64 makekey(float v, int idx) {
  return ((u64)mono(v) << 32) | (u32)(~(u32)idx);
}
__device__ __forceinline__ int key_idx(u64 k) { return (int)(~(u32)k); }
__device__ __forceinline__ float key_val(u64 k) { return unmono((u32)(k >> 32)); }

// Branchless compare-exchange: a = max, b = min.
__device__ __forceinline__ void cswap(u64& a, u64& b) {
  const bool c = a > b;
  const u64 hi = c ? a : b;
  const u64 lo = c ? b : a;
  a = hi; b = lo;
}

__device__ __forceinline__ void compute_elem(
    int s, int r, bool rmask, int sm,
    float rv0, float rv1, float rv2, int ri0, int ri1, int ri2,
    float a0, int b0, float a1, int b1, float a2, int b2,
    float& oscore, float& ocorr) {
  const float rv = (s == ri0) ? rv0 : (s == ri1) ? rv1 : (s == ri2) ? rv2 : 0.0f;
  const float sv = (r == b0) ? a0 : (r == b1) ? a1 : (r == b2) ? a2 : 0.0f;
  oscore = 0.5f * (rv + sv);
  const bool m = rmask && (sm != 0);
  ocorr = (((rv > 0.0f) || (sv > 0.0f)) && m) ? 1.0f : 0.0f;
}

// One block per p (512 blocks x 512 threads). Everything block-local:
//   Phase A: row top-3 (wave per row, 32 rows/wave) -> LDS
//   Phase B: col top-3 (thread per column, two 128-row halves + LDS merge)
//   Phase C: dense write of score_map + corr_map from LDS/registers
// No global intermediates, single launch.
__global__ __launch_bounds__(512) void fused_kernel(
    const float* __restrict__ score,
    const int* __restrict__ rmaskp, const int* __restrict__ smaskp,
    float* __restrict__ out) {
  const int p    = blockIdx.x;
  const int tid  = threadIdx.x;
  const int wave = tid >> 6;
  const int lane = tid & 63;

  __shared__ float rowv[3][Rn];
  __shared__ int   rowi[3][Rn];
  __shared__ u64   colk[3][Sn];   // half-1 partial keys for the merge
  __shared__ float colv[3][Sn];
  __shared__ int   coli[3][Sn];
  __shared__ int   rmlds[Rn];

  const float* tile = score + (size_t)p * Rn * Sn;

  if (tid < Rn) rmlds[tid] = rmaskp[p * Rn + tid];

  // ---- Phase A: row top-3. Wave w owns rows [w*32, w*32+32). Proven
  // sort-4 + 3x(wave-max + pop) butterfly from rounds 2/3.
  for (int i = 0; i < 32; ++i) {
    const int r = wave * 32 + i;
    const float4 v = reinterpret_cast<const float4*>(tile + (size_t)r * Sn)[lane];
    const int b = lane * 4;
    u64 a0 = makekey(v.x, b + 0);
    u64 a1 = makekey(v.y, b + 1);
    u64 a2 = makekey(v.z, b + 2);
    u64 a3 = makekey(v.w, b + 3);
    cswap(a0, a1); cswap(a2, a3); cswap(a0, a2); cswap(a1, a3); cswap(a1, a2);
    u64 t0 = a0, t1 = a1, t2 = a2;

    u64 res0 = 0, res1 = 0, res2 = 0;
    #pragma unroll
    for (int j = 0; j < 3; ++j) {
      u64 m = t0;
      #pragma unroll
      for (int off = 1; off < 64; off <<= 1) {
        const u64 o = __shfl_xor(m, off);
        m = (o > m) ? o : m;
      }
      const bool hit = (t0 == m);   // keys unique: exactly one lane pops
      t0 = hit ? t1 : t0;
      t1 = hit ? t2 : t1;
      t2 = hit ? 0ull : t2;
      if (j == 0) res0 = m; else if (j == 1) res1 = m; else res2 = m;
    }
    if (lane == 0) {
      rowv[0][r] = expf(key_val(res0)); rowi[0][r] = key_idx(res0);
      rowv[1][r] = expf(key_val(res1)); rowi[1][r] = key_idx(res1);
      rowv[2][r] = expf(key_val(res2)); rowi[2][r] = key_idx(res2);
    }
  }

  // ---- Phase B: col top-3. Thread t handles column s = t&255 over row-half
  // h = t>>8 (waves 0-3 -> rows 0..127, waves 4-7 -> rows 128..255).
  {
    const int s = tid & (Sn - 1);
    const int h = tid >> 8;
    const float* base = tile + (size_t)h * 128 * Sn + s;
    u64 t0 = 0, t1 = 0, t2 = 0;
    #pragma unroll 8
    for (int r = 0; r < 128; ++r) {
      u64 k = makekey(base[(size_t)r * Sn], h * 128 + r);
      cswap(t0, k); cswap(t1, k); cswap(t2, k);
    }
    if (h == 1) {
      colk[0][s] = t0; colk[1][s] = t1; colk[2][s] = t2;
    }
    __syncthreads();
    if (h == 0) {
      u64 k;
      k = colk[0][s]; cswap(t0, k); cswap(t1, k); cswap(t2, k);
      k = colk[1][s]; cswap(t0, k); cswap(t1, k); cswap(t2, k);
      k = colk[2][s]; cswap(t0, k); cswap(t1, k); cswap(t2, k);
      colv[0][s] = expf(key_val(t0)); coli[0][s] = key_idx(t0);
      colv[1][s] = expf(key_val(t1)); coli[1][s] = key_idx(t1);
      colv[2][s] = expf(key_val(t2)); coli[2][s] = key_idx(t2);
    }
    __syncthreads();
  }

  // ---- Phase C: dense write. Wave w writes rows [w*32, w*32+32); lane owns
  // columns [lane*4, lane*4+4). Col-side data is row-invariant: registers.
  const int sbase = lane * 4;
  float cv0x = colv[0][sbase + 0], cv0y = colv[0][sbase + 1],
        cv0z = colv[0][sbase + 2], cv0w = colv[0][sbase + 3];
  float cv1x = colv[1][sbase + 0], cv1y = colv[1][sbase + 1],
        cv1z = colv[1][sbase + 2], cv1w = colv[1][sbase + 3];
  float cv2x = colv[2][sbase + 0], cv2y = colv[2][sbase + 1],
        cv2z = colv[2][sbase + 2], cv2w = colv[2][sbase + 3];
  int ci0x = coli[0][sbase + 0], ci0y = coli[0][sbase + 1],
      ci0z = coli[0][sbase + 2], ci0w = coli[0][sbase + 3];
  int ci1x = coli[1][sbase + 0], ci1y = coli[1][sbase + 1],
      ci1z = coli[1][sbase + 2], ci1w = coli[1][sbase + 3];
  int ci2x = coli[2][sbase + 0], ci2y = coli[2][sbase + 1],
      ci2z = coli[2][sbase + 2], ci2w = coli[2][sbase + 3];
  const int4 sm = reinterpret_cast<const int4*>(smaskp + (size_t)p * Sn)[lane];
  const size_t N = (size_t)Pn * Rn * Sn;
  float* outp = out + (size_t)p * Rn * Sn;

  #pragma unroll 4
  for (int i = 0; i < 32; ++i) {
    const int r = wave * 32 + i;
    const float rv0 = rowv[0][r], rv1 = rowv[1][r], rv2 = rowv[2][r];
    const int   ri0 = rowi[0][r], ri1 = rowi[1][r], ri2 = rowi[2][r];
    const bool  rm  = rmlds[r] != 0;

    float4 osc, oco;
    compute_elem(sbase + 0, r, rm, sm.x, rv0, rv1, rv2, ri0, ri1, ri2,
                 cv0x, ci0x, cv1x, ci1x, cv2x, ci2x, osc.x, oco.x);
    compute_elem(sbase + 1, r, rm, sm.y, rv0, rv1, rv2, ri0, ri1, ri2,
                 cv0y, ci0y, cv1y, ci1y, cv2y, ci2y, osc.y, oco.y);
    compute_elem(sbase + 2, r, rm, sm.z, rv0, rv1, rv2, ri0, ri1, ri2,
                 cv0z, ci0z, cv1z, ci1z, cv2z, ci2z, osc.z, oco.z);
    compute_elem(sbase + 3, r, rm, sm.w, rv0, rv1, rv2, ri0, ri1, ri2,
                 cv0w, ci0w, cv1w, ci1w, cv2w, ci2w, osc.w, oco.w);

    reinterpret_cast<float4*>(outp + (size_t)r * Sn)[lane]     = osc;
    reinterpret_cast<float4*>(outp + N + (size_t)r * Sn)[lane] = oco;
  }
}

extern "C" void kernel_launch(void* const* d_in, const int* in_sizes, int n_in,
                              void* d_out, int out_size, void* d_ws, size_t ws_size,
                              hipStream_t stream) {
  const float* score = (const float*)d_in[0];
  // d_in[1] = node_corr_scores: unused (conditional=False in reference)
  const int* rmask = (const int*)d_in[2];
  const int* smask = (const int*)d_in[3];
  float* out = (float*)d_out;

  fused_kernel<<<Pn, 512, 0, stream>>>(score, rmask, smask, out);
}

// Round 5
// 466.249 us; speedup vs baseline: 1.0359x; 1.0359x over previous
//
#include <hip/hip_runtime.h>
#include <math.h>
#include <stdint.h>

// Problem shape (fixed by setup_inputs): P=512, R=256, S=256, K=3, threshold=0.
#define Pn 512
#define Rn 256
#define Sn 256

typedef unsigned long long u64;
typedef unsigned int u32;

// ---- u64 key machinery (row butterfly only; proven R2-R4) ----
__device__ __forceinline__ u32 mono(float f) {
  u32 u = __float_as_uint(f);
  return (u & 0x80000000u) ? ~u : (u | 0x80000000u);
}
__device__ __forceinline__ float unmono(u32 m) {
  u32 bits = (m & 0x80000000u) ? (m & 0x7FFFFFFFu) : ~m;
  return __uint_as_float(bits);
}
__device__ __forceinline__ u64 makekey(float v, int idx) {
  return ((u64)mono(v) << 32) | (u32)(~(u32)idx);
}
__device__ __forceinline__ int key_idx(u64 k) { return (int)(~(u32)k); }
__device__ __forceinline__ float key_val(u64 k) { return unmono((u32)(k >> 32)); }
__device__ __forceinline__ void cswap(u64& a, u64& b) {
  const bool c = a > b;
  const u64 hi = c ? a : b;
  const u64 lo = c ? b : a;
  a = hi; b = lo;
}

// ---- branchless float top-3 insert. Strict >, so when scanning in
// ascending index order (and slabs merged in ascending order), ties keep
// the smaller index = lax.top_k semantics. ----
__device__ __forceinline__ void ins3f(float v, int i,
    float& t0, int& i0, float& t1, int& i1, float& t2, int& i2) {
  const bool b0 = v > t0, b1 = v > t1, b2 = v > t2;
  const float nt0 = b0 ? v : t0;
  const int   ni0 = b0 ? i : i0;
  const float nt1 = b0 ? t0 : (b1 ? v : t1);
  const int   ni1 = b0 ? i0 : (b1 ? i : i1);
  const float nt2 = b1 ? t1 : (b2 ? v : t2);
  const int   ni2 = b1 ? i1 : (b2 ? i : i2);
  t0 = nt0; i0 = ni0; t1 = nt1; i1 = ni1; t2 = nt2; i2 = ni2;
}

#define COLSLAB_BLOCKS (Pn * 4)       // (p, 64-row slab), thread-per-column
#define ROW_BLOCKS ((Pn * Rn) / 4)    // 4 rows per block, wave-per-row

// K1: col-slab partial top-3 (first in grid: longer-running blocks) +
// row top-3 (wave-per-row butterfly). One launch so both read streams of
// the input overlap; the second stream mostly hits L2/L3.
__global__ __launch_bounds__(256) void top3_kernel(
    const float* __restrict__ score,
    float* __restrict__ refv, int* __restrict__ refi,
    float* __restrict__ colpv, int* __restrict__ colpi) {
  const size_t PS = (size_t)Pn * Sn;
  if (blockIdx.x < COLSLAB_BLOCKS) {
    const int p    = blockIdx.x >> 2;
    const int slab = blockIdx.x & 3;
    const int s    = threadIdx.x;
    const float* base = score + (size_t)p * Rn * Sn + (size_t)slab * 64 * Sn + s;
    float t0 = -INFINITY, t1 = -INFINITY, t2 = -INFINITY;
    int   i0 = -1, i1 = -1, i2 = -1;
    const int r0 = slab * 64;
    #pragma unroll 8
    for (int r = 0; r < 64; ++r)
      ins3f(base[(size_t)r * Sn], r0 + r, t0, i0, t1, i1, t2, i2);
    const size_t o = (size_t)p * Sn + s;
    colpv[(slab * 3 + 0) * PS + o] = t0; colpi[(slab * 3 + 0) * PS + o] = i0;
    colpv[(slab * 3 + 1) * PS + o] = t1; colpi[(slab * 3 + 1) * PS + o] = i1;
    colpv[(slab * 3 + 2) * PS + o] = t2; colpi[(slab * 3 + 2) * PS + o] = i2;
  } else {
    const int bid  = blockIdx.x - COLSLAB_BLOCKS;
    const int row  = (bid * blockDim.x + threadIdx.x) >> 6;  // p*Rn + r
    const int lane = threadIdx.x & 63;
    const float4 v = reinterpret_cast<const float4*>(score + (size_t)row * Sn)[lane];
    const int b = lane * 4;
    u64 a0 = makekey(v.x, b + 0);
    u64 a1 = makekey(v.y, b + 1);
    u64 a2 = makekey(v.z, b + 2);
    u64 a3 = makekey(v.w, b + 3);
    cswap(a0, a1); cswap(a2, a3); cswap(a0, a2); cswap(a1, a3); cswap(a1, a2);
    u64 t0 = a0, t1 = a1, t2 = a2;

    u64 res0 = 0, res1 = 0, res2 = 0;
    #pragma unroll
    for (int j = 0; j < 3; ++j) {
      u64 m = t0;
      #pragma unroll
      for (int off = 1; off < 64; off <<= 1) {
        const u64 o = __shfl_xor(m, off);
        m = (o > m) ? o : m;
      }
      const bool hit = (t0 == m);   // keys unique: exactly one lane pops
      t0 = hit ? t1 : t0;
      t1 = hit ? t2 : t1;
      t2 = hit ? 0ull : t2;
      if (j == 0) res0 = m; else if (j == 1) res1 = m; else res2 = m;
    }
    if (lane == 0) {
      const size_t o = (size_t)row * 3;
      refv[o + 0] = expf(key_val(res0)); refi[o + 0] = key_idx(res0);
      refv[o + 1] = expf(key_val(res1)); refi[o + 1] = key_idx(res1);
      refv[o + 2] = expf(key_val(res2)); refi[o + 2] = key_idx(res2);
    }
  }
}

__device__ __forceinline__ void compute_elem(
    int s, int r, bool rmask, int sm,
    float rv0, float rv1, float rv2, int ri0, int ri1, int ri2,
    float a0, int b0, float a1, int b1, float a2, int b2,
    float& oscore, float& ocorr) {
  const float rv = (s == ri0) ? rv0 : (s == ri1) ? rv1 : (s == ri2) ? rv2 : 0.0f;
  const float sv = (r == b0) ? a0 : (r == b1) ? a1 : (r == b2) ? a2 : 0.0f;
  oscore = 0.5f * (rv + sv);
  const bool m = rmask && (sm != 0);
  ocorr = (((rv > 0.0f) || (sv > 0.0f)) && m) ? 1.0f : 0.0f;
}

// K2: merge the 4 slab partials per column in registers (each wave merges
// its own lanes' 4 columns; redundant across the block's 4 waves but L1-hot
// and branch-free), apply exp, then stream 64 rows of both outputs.
__global__ __launch_bounds__(256) void write_kernel(
    const float* __restrict__ refv, const int* __restrict__ refi,
    const float* __restrict__ colpv, const int* __restrict__ colpi,
    const int* __restrict__ rmaskp, const int* __restrict__ smaskp,
    float* __restrict__ out) {
  const int p     = blockIdx.x >> 2;
  const int rbase = (blockIdx.x & 3) * 64;
  const int warp  = threadIdx.x >> 6;
  const int lane  = threadIdx.x & 63;
  const size_t PS = (size_t)Pn * Sn;
  const size_t N  = (size_t)Pn * Rn * Sn;
  const size_t cb = (size_t)p * Sn;

  // Init from slab 0 (already rank-sorted), insert slabs 1..3 in ascending
  // order, keys in rank order — strict > keeps earlier slab on ties.
  float4 T0 = reinterpret_cast<const float4*>(colpv + 0 * PS + cb)[lane];
  float4 T1 = reinterpret_cast<const float4*>(colpv + 1 * PS + cb)[lane];
  float4 T2 = reinterpret_cast<const float4*>(colpv + 2 * PS + cb)[lane];
  int4   I0 = reinterpret_cast<const int4*>(colpi + 0 * PS + cb)[lane];
  int4   I1 = reinterpret_cast<const int4*>(colpi + 1 * PS + cb)[lane];
  int4   I2 = reinterpret_cast<const int4*>(colpi + 2 * PS + cb)[lane];
  #pragma unroll
  for (int sk = 3; sk < 12; ++sk) {
    const float4 V = reinterpret_cast<const float4*>(colpv + (size_t)sk * PS + cb)[lane];
    const int4   I = reinterpret_cast<const int4*>(colpi + (size_t)sk * PS + cb)[lane];
    ins3f(V.x, I.x, T0.x, I0.x, T1.x, I1.x, T2.x, I2.x);
    ins3f(V.y, I.y, T0.y, I0.y, T1.y, I1.y, T2.y, I2.y);
    ins3f(V.z, I.z, T0.z, I0.z, T1.z, I1.z, T2.z, I2.z);
    ins3f(V.w, I.w, T0.w, I0.w, T1.w, I1.w, T2.w, I2.w);
  }
  T0.x = expf(T0.x); T0.y = expf(T0.y); T0.z = expf(T0.z); T0.w = expf(T0.w);
  T1.x = expf(T1.x); T1.y = expf(T1.y); T1.z = expf(T1.z); T1.w = expf(T1.w);
  T2.x = expf(T2.x); T2.y = expf(T2.y); T2.z = expf(T2.z); T2.w = expf(T2.w);

  const int4 sm = reinterpret_cast<const int4*>(smaskp + cb)[lane];
  const int sbase = lane * 4;
  float* outp = out + (size_t)p * Rn * Sn;

  #pragma unroll 4
  for (int it = 0; it < 16; ++it) {
    const int r   = rbase + it * 4 + warp;
    const int row = p * Rn + r;
    const size_t rb = (size_t)row * 3;
    const float rv0 = refv[rb + 0], rv1 = refv[rb + 1], rv2 = refv[rb + 2];
    const int   ri0 = refi[rb + 0], ri1 = refi[rb + 1], ri2 = refi[rb + 2];
    const bool  rm  = rmaskp[row] != 0;

    float4 osc, oco;
    compute_elem(sbase + 0, r, rm, sm.x, rv0, rv1, rv2, ri0, ri1, ri2,
                 T0.x, I0.x, T1.x, I1.x, T2.x, I2.x, osc.x, oco.x);
    compute_elem(sbase + 1, r, rm, sm.y, rv0, rv1, rv2, ri0, ri1, ri2,
                 T0.y, I0.y, T1.y, I1.y, T2.y, I2.y, osc.y, oco.y);
    compute_elem(sbase + 2, r, rm, sm.z, rv0, rv1, rv2, ri0, ri1, ri2,
                 T0.z, I0.z, T1.z, I1.z, T2.z, I2.z, osc.z, oco.z);
    compute_elem(sbase + 3, r, rm, sm.w, rv0, rv1, rv2, ri0, ri1, ri2,
                 T0.w, I0.w, T1.w, I1.w, T2.w, I2.w, osc.w, oco.w);

    reinterpret_cast<float4*>(outp + (size_t)r * Sn)[lane]     = osc;
    reinterpret_cast<float4*>(outp + N + (size_t)r * Sn)[lane] = oco;
  }
}

extern "C" void kernel_launch(void* const* d_in, const int* in_sizes, int n_in,
                              void* d_out, int out_size, void* d_ws, size_t ws_size,
                              hipStream_t stream) {
  const float* score = (const float*)d_in[0];
  // d_in[1] = node_corr_scores: unused (conditional=False in reference)
  const int* rmask = (const int*)d_in[2];
  const int* smask = (const int*)d_in[3];
  float* out = (float*)d_out;

  const size_t PR = (size_t)Pn * Rn;
  const size_t PS = (size_t)Pn * Sn;
  // Workspace: refv/refi (1.5 MB each), col partials (6.3 MB each)
  float* refv  = (float*)d_ws;              // 3*PR floats
  int*   refi  = (int*)(refv + 3 * PR);     // 3*PR ints
  float* colpv = (float*)(refi + 3 * PR);   // 12*PS floats (slab,k planes)
  int*   colpi = (int*)(colpv + 12 * PS);   // 12*PS ints

  top3_kernel<<<COLSLAB_BLOCKS + ROW_BLOCKS, 256, 0, stream>>>(
      score, refv, refi, colpv, colpi);
  write_kernel<<<(Pn * Rn) / 64, 256, 0, stream>>>(
      refv, refi, colpv, colpi, rmask, smask, out);
}

// Round 6
// 420.893 us; speedup vs baseline: 1.1475x; 1.1078x over previous
//
#include <hip/hip_runtime.h>
#include <math.h>
#include <stdint.h>

// Problem shape (fixed by setup_inputs): P=512, R=256, S=256, K=3, threshold=0.
#define Pn 512
#define Rn 256
#define Sn 256

typedef unsigned long long u64;
typedef unsigned int u32;

// ---- u64 key machinery for the row butterfly (proven R2-R5) ----
__device__ __forceinline__ u32 mono(float f) {
  u32 u = __float_as_uint(f);
  return (u & 0x80000000u) ? ~u : (u | 0x80000000u);
}
__device__ __forceinline__ float unmono(u32 m) {
  u32 bits = (m & 0x80000000u) ? (m & 0x7FFFFFFFu) : ~m;
  return __uint_as_float(bits);
}
__device__ __forceinline__ u64 makekey(float v, int idx) {
  return ((u64)mono(v) << 32) | (u32)(~(u32)idx);
}
__device__ __forceinline__ int key_idx(u64 k) { return (int)(~(u32)k); }
__device__ __forceinline__ float key_val(u64 k) { return unmono((u32)(k >> 32)); }
__device__ __forceinline__ void cswap(u64& a, u64& b) {
  const bool c = a > b;
  const u64 hi = c ? a : b;
  const u64 lo = c ? b : a;
  a = hi; b = lo;
}

// ---- branchless float top-3 insert (proven R5). Strict >, ascending-index
// insert order => smaller index wins ties = lax.top_k semantics. ----
__device__ __forceinline__ void ins3f(float v, int i,
    float& t0, int& i0, float& t1, int& i1, float& t2, int& i2) {
  const bool b0 = v > t0, b1 = v > t1, b2 = v > t2;
  const float nt0 = b0 ? v : t0;
  const int   ni0 = b0 ? i : i0;
  const float nt1 = b0 ? t0 : (b1 ? v : t1);
  const int   ni1 = b0 ? i0 : (b1 ? i : i1);
  const float nt2 = b1 ? t1 : (b2 ? v : t2);
  const int   ni2 = b1 ? i1 : (b2 ? i : i2);
  t0 = nt0; i0 = ni0; t1 = nt1; i1 = ni1; t2 = nt2; i2 = ni2;
}

// K1: col-slab partial top-3 (R5's proven branch). Block = (p, 64-row slab),
// thread-per-column, coalesced row loads. Single full read of the input.
__global__ __launch_bounds__(256) void colslab_kernel(
    const float* __restrict__ score,
    float* __restrict__ colpv, int* __restrict__ colpi) {
  const size_t PS = (size_t)Pn * Sn;
  const int p    = blockIdx.x >> 2;
  const int slab = blockIdx.x & 3;
  const int s    = threadIdx.x;
  const float* base = score + (size_t)p * Rn * Sn + (size_t)slab * 64 * Sn + s;
  float t0 = -INFINITY, t1 = -INFINITY, t2 = -INFINITY;
  int   i0 = -1, i1 = -1, i2 = -1;
  const int r0 = slab * 64;
  #pragma unroll 8
  for (int r = 0; r < 64; ++r)
    ins3f(base[(size_t)r * Sn], r0 + r, t0, i0, t1, i1, t2, i2);
  const size_t o = (size_t)p * Sn + s;
  colpv[(slab * 3 + 0) * PS + o] = t0; colpi[(slab * 3 + 0) * PS + o] = i0;
  colpv[(slab * 3 + 1) * PS + o] = t1; colpi[(slab * 3 + 1) * PS + o] = i1;
  colpv[(slab * 3 + 2) * PS + o] = t2; colpi[(slab * 3 + 2) * PS + o] = i2;
}

__device__ __forceinline__ void compute_elem(
    int s, int r, bool rmask, int sm,
    float rv0, float rv1, float rv2, int ri0, int ri1, int ri2,
    float a0, int b0, float a1, int b1, float a2, int b2,
    float& oscore, float& ocorr) {
  const float rv = (s == ri0) ? rv0 : (s == ri1) ? rv1 : (s == ri2) ? rv2 : 0.0f;
  const float sv = (r == b0) ? a0 : (r == b1) ? a1 : (r == b2) ? a2 : 0.0f;
  oscore = 0.5f * (rv + sv);
  const bool m = rmask && (sm != 0);
  ocorr = (((rv > 0.0f) || (sv > 0.0f)) && m) ? 1.0f : 0.0f;
}

// K2: per (p, 64-row slab) block. Merge col-slab partials in registers
// (each lane owns 4 columns), then per row: re-read the row (L3-hot),
// wave-butterfly row top-3 (result lands in ALL lanes), compute, write.
// Row tops never touch global memory.
__global__ __launch_bounds__(256) void write_kernel(
    const float* __restrict__ score,
    const float* __restrict__ colpv, const int* __restrict__ colpi,
    const int* __restrict__ rmaskp, const int* __restrict__ smaskp,
    float* __restrict__ out) {
  const int p     = blockIdx.x >> 2;
  const int rbase = (blockIdx.x & 3) * 64;
  const int warp  = threadIdx.x >> 6;
  const int lane  = threadIdx.x & 63;
  const size_t PS = (size_t)Pn * Sn;
  const size_t N  = (size_t)Pn * Rn * Sn;
  const size_t cb = (size_t)p * Sn;

  // Merge 4 slab partials per column (ascending slab order, rank order).
  float4 T0 = reinterpret_cast<const float4*>(colpv + 0 * PS + cb)[lane];
  float4 T1 = reinterpret_cast<const float4*>(colpv + 1 * PS + cb)[lane];
  float4 T2 = reinterpret_cast<const float4*>(colpv + 2 * PS + cb)[lane];
  int4   I0 = reinterpret_cast<const int4*>(colpi + 0 * PS + cb)[lane];
  int4   I1 = reinterpret_cast<const int4*>(colpi + 1 * PS + cb)[lane];
  int4   I2 = reinterpret_cast<const int4*>(colpi + 2 * PS + cb)[lane];
  #pragma unroll
  for (int sk = 3; sk < 12; ++sk) {
    const float4 V = reinterpret_cast<const float4*>(colpv + (size_t)sk * PS + cb)[lane];
    const int4   I = reinterpret_cast<const int4*>(colpi + (size_t)sk * PS + cb)[lane];
    ins3f(V.x, I.x, T0.x, I0.x, T1.x, I1.x, T2.x, I2.x);
    ins3f(V.y, I.y, T0.y, I0.y, T1.y, I1.y, T2.y, I2.y);
    ins3f(V.z, I.z, T0.z, I0.z, T1.z, I1.z, T2.z, I2.z);
    ins3f(V.w, I.w, T0.w, I0.w, T1.w, I1.w, T2.w, I2.w);
  }
  T0.x = expf(T0.x); T0.y = expf(T0.y); T0.z = expf(T0.z); T0.w = expf(T0.w);
  T1.x = expf(T1.x); T1.y = expf(T1.y); T1.z = expf(T1.z); T1.w = expf(T1.w);
  T2.x = expf(T2.x); T2.y = expf(T2.y); T2.z = expf(T2.z); T2.w = expf(T2.w);

  const int4 sm = reinterpret_cast<const int4*>(smaskp + cb)[lane];
  const int sbase = lane * 4;
  const float* tile = score + (size_t)p * Rn * Sn;
  float* outp = out + (size_t)p * Rn * Sn;

  #pragma unroll 2
  for (int it = 0; it < 16; ++it) {
    const int r = rbase + it * 4 + warp;
    // Row top-3 butterfly (keys unique via embedded index).
    const float4 v = reinterpret_cast<const float4*>(tile + (size_t)r * Sn)[lane];
    const int b = lane * 4;
    u64 a0 = makekey(v.x, b + 0);
    u64 a1 = makekey(v.y, b + 1);
    u64 a2 = makekey(v.z, b + 2);
    u64 a3 = makekey(v.w, b + 3);
    cswap(a0, a1); cswap(a2, a3); cswap(a0, a2); cswap(a1, a3); cswap(a1, a2);
    u64 t0 = a0, t1 = a1, t2 = a2;
    u64 res0 = 0, res1 = 0, res2 = 0;
    #pragma unroll
    for (int j = 0; j < 3; ++j) {
      u64 m = t0;
      #pragma unroll
      for (int off = 1; off < 64; off <<= 1) {
        const u64 o = __shfl_xor(m, off);
        m = (o > m) ? o : m;
      }
      const bool hit = (t0 == m);
      t0 = hit ? t1 : t0;
      t1 = hit ? t2 : t1;
      t2 = hit ? 0ull : t2;
      if (j == 0) res0 = m; else if (j == 1) res1 = m; else res2 = m;
    }
    const float rv0 = expf(key_val(res0));
    const float rv1 = expf(key_val(res1));
    const float rv2 = expf(key_val(res2));
    const int   ri0 = key_idx(res0), ri1 = key_idx(res1), ri2 = key_idx(res2);
    const bool  rm  = rmaskp[p * Rn + r] != 0;   // wave-uniform scalar load

    float4 osc, oco;
    compute_elem(sbase + 0, r, rm, sm.x, rv0, rv1, rv2, ri0, ri1, ri2,
                 T0.x, I0.x, T1.x, I1.x, T2.x, I2.x, osc.x, oco.x);
    compute_elem(sbase + 1, r, rm, sm.y, rv0, rv1, rv2, ri0, ri1, ri2,
                 T0.y, I0.y, T1.y, I1.y, T2.y, I2.y, osc.y, oco.y);
    compute_elem(sbase + 2, r, rm, sm.z, rv0, rv1, rv2, ri0, ri1, ri2,
                 T0.z, I0.z, T1.z, I1.z, T2.z, I2.z, osc.z, oco.z);
    compute_elem(sbase + 3, r, rm, sm.w, rv0, rv1, rv2, ri0, ri1, ri2,
                 T0.w, I0.w, T1.w, I1.w, T2.w, I2.w, osc.w, oco.w);

    reinterpret_cast<float4*>(outp + (size_t)r * Sn)[lane]     = osc;
    reinterpret_cast<float4*>(outp + N + (size_t)r * Sn)[lane] = oco;
  }
}

extern "C" void kernel_launch(void* const* d_in, const int* in_sizes, int n_in,
                              void* d_out, int out_size, void* d_ws, size_t ws_size,
                              hipStream_t stream) {
  const float* score = (const float*)d_in[0];
  // d_in[1] = node_corr_scores: unused (conditional=False in reference)
  const int* rmask = (const int*)d_in[2];
  const int* smask = (const int*)d_in[3];
  float* out = (float*)d_out;

  const size_t PS = (size_t)Pn * Sn;
  // Workspace: col slab partials only (12 planes of values + indices).
  float* colpv = (float*)d_ws;              // 12*PS floats
  int*   colpi = (int*)(colpv + 12 * PS);   // 12*PS ints

  colslab_kernel<<<Pn * 4, 256, 0, stream>>>(score, colpv, colpi);
  write_kernel<<<Pn * 4, 256, 0, stream>>>(score, colpv, colpi,
                                           rmask, smask, out);
}